// Round 4
// baseline (144.829 us; speedup 1.0000x reference)
//
#include <hip/hip_runtime.h>
#include <hip/hip_bf16.h>
#include <hip/hip_fp16.h>

// minGRU parallel scan, B=4 L=8192 DX=512 DH=512.
// h_t = a_t h_{t-1} + b_t, a=sigmoid(-k), b=sigmoid(k)*g(p); linear-space chunked scan.
// R4: barrier-free streaming GEMM — weights held in 128 VGPRs per wave (full K),
// x read directly from global in A-fragment order (L3-resident), no LDS at all.

#define BB 4
#define LL 8192
#define MM (BB*LL)        // 32768 rows
#define NC 128            // chunks per batch
#define CHUNK 64          // L / NC

typedef __attribute__((ext_vector_type(8))) short bf16x8;
typedef __attribute__((ext_vector_type(4))) float f32x4;

__device__ inline unsigned f2bf(float f) {
    unsigned u = __float_as_uint(f);
    return ((u + 0x7FFFu + ((u >> 16) & 1u)) >> 16) & 0xFFFFu;
}

// x f32 [row][k] -> bf16 A-fragment order:
// frag f = rb*16 + kstep (rb = row/16, kstep = k/32), lane = lg*16 + (row&15),
// holds x[row][kstep*32 + lg*8 .. +8]. Stored at xf[f*512 + lane*8].
__global__ void cvt_xfrag(const float* __restrict__ in, unsigned short* __restrict__ out) {
    int t = blockIdx.x * 256 + threadIdx.x;     // 0 .. 2M-1
    int lane = t & 63, f = t >> 6;
    int kstep = f & 15, rb = f >> 4;
    int row = rb * 16 + (lane & 15);
    int k = kstep * 32 + (lane >> 4) * 8;
    const float* p = in + (size_t)row * 512 + k;
    float4 v0 = *(const float4*)p;
    float4 v1 = *(const float4*)(p + 4);
    uint4 o;
    o.x = f2bf(v0.x) | (f2bf(v0.y) << 16);
    o.y = f2bf(v0.z) | (f2bf(v0.w) << 16);
    o.z = f2bf(v1.x) | (f2bf(v1.y) << 16);
    o.w = f2bf(v1.z) | (f2bf(v1.w) << 16);
    *(uint4*)(out + (size_t)t * 8) = o;
}

// Pack both weights into MFMA B-fragment order (validated R3):
// frag u = (((ntile*8 + ks)*2 + kk)*8 + nf2)*64 + lane holds W[n][k..k+8],
// n = ntile*128 + nf2*16 + (lane&15), k = ks*64 + kk*32 + (lane>>4)*8.
__global__ void cvt_wfrag(const float* __restrict__ Wz, const float* __restrict__ Wh,
                          unsigned short* __restrict__ wzf, unsigned short* __restrict__ whf) {
    int t = blockIdx.x * 256 + threadIdx.x;    // 0..65535
    int wsel = t >> 15;
    int u = t & 32767;
    int lane = u & 63, lg = lane >> 4, lr = lane & 15;
    int nf2 = (u >> 6) & 7;
    int kk = (u >> 9) & 1;
    int ks = (u >> 10) & 7;
    int ntile = (u >> 13) & 3;
    int n = ntile * 128 + nf2 * 16 + lr;
    int k = ks * 64 + kk * 32 + lg * 8;
    const float* W = wsel ? Wh : Wz;
    unsigned short* o = wsel ? whf : wzf;
    const float* p = W + (size_t)n * 512 + k;
    float4 v0 = *(const float4*)p;
    float4 v1 = *(const float4*)(p + 4);
    uint4 ov;
    ov.x = f2bf(v0.x) | (f2bf(v0.y) << 16);
    ov.y = f2bf(v0.z) | (f2bf(v0.w) << 16);
    ov.z = f2bf(v1.x) | (f2bf(v1.y) << 16);
    ov.w = f2bf(v1.z) | (f2bf(v1.w) << 16);
    *(uint4*)(o + (size_t)u * 8) = ov;
}

// Barrier-free streaming GEMM + gate epilogue + fused chunk aggregates.
// Block = 4 waves; wave owns n-slice ns (16 cols), full K in registers.
// grid.x = 512: npart = bx&7 (8 n-groups of 64), mgrp = bx>>3 (512 rows each).
__global__ __launch_bounds__(256, 2) void gemm_gate(
    const unsigned short* __restrict__ xf, const unsigned short* __restrict__ wzf,
    const unsigned short* __restrict__ whf,
    const float* __restrict__ bz, const float* __restrict__ bh,
    uint4* __restrict__ pkf, float2* __restrict__ agg)
{
    const int tid = threadIdx.x;
    const int wid = tid >> 6, lane = tid & 63;
    const int lr = lane & 15, lg = lane >> 4;
    const int npart = blockIdx.x & 7;
    const int mgrp  = blockIdx.x >> 3;
    const int ns = npart * 4 + wid;            // 0..31

    // Load both weight matrices' fragments for this n-slice, full K: 128 VGPRs.
    bf16x8 wz[16], wh[16];
#pragma unroll
    for (int kstep = 0; kstep < 16; ++kstep) {
        int ks = kstep >> 1, kk = kstep & 1;
        size_t fo = ((((size_t)(ns >> 3) * 8 + ks) * 2 + kk) * 8 + (ns & 7)) * 512 + lane * 8;
        wz[kstep] = *(const bf16x8*)(wzf + fo);
        wh[kstep] = *(const bf16x8*)(whf + fo);
    }
    const int h = ns * 16 + lr;
    const float bzv = bz[h], bhv = bh[h];

    for (int mt = 0; mt < 8; ++mt) {
        const int rb0 = mgrp * 32 + mt * 4;                 // row-block (16 rows each)
        const unsigned short* xb = xf + (size_t)rb0 * 16 * 512 + lane * 8;
        f32x4 acck[4] = {{0.f,0.f,0.f,0.f},{0.f,0.f,0.f,0.f},{0.f,0.f,0.f,0.f},{0.f,0.f,0.f,0.f}};
        f32x4 accp[4] = {{0.f,0.f,0.f,0.f},{0.f,0.f,0.f,0.f},{0.f,0.f,0.f,0.f},{0.f,0.f,0.f,0.f}};
        bf16x8 af[4][4];                                    // [pipeline slot][mf], all-static idx
#pragma unroll
        for (int d = 0; d < 4; ++d)
#pragma unroll
            for (int mf = 0; mf < 4; ++mf)
                af[d][mf] = *(const bf16x8*)(xb + ((size_t)mf * 16 + d) * 512);
#pragma unroll
        for (int kstep = 0; kstep < 16; ++kstep) {
            const int s = kstep & 3;
#pragma unroll
            for (int mf = 0; mf < 4; ++mf) {
                acck[mf] = __builtin_amdgcn_mfma_f32_16x16x32_bf16(af[s][mf], wz[kstep], acck[mf], 0, 0, 0);
                accp[mf] = __builtin_amdgcn_mfma_f32_16x16x32_bf16(af[s][mf], wh[kstep], accp[mf], 0, 0, 0);
            }
            if (kstep < 12) {
#pragma unroll
                for (int mf = 0; mf < 4; ++mf)
                    af[s][mf] = *(const bf16x8*)(xb + ((size_t)mf * 16 + kstep + 4) * 512);
            }
        }

        // Epilogue. C/D layout: col=lane&15 (=h-lr), row=(lane>>4)*4+j [m89-verified].
        // This m-tile is exactly chunk cg = mgrp*8 + mt (= b*128 + c).
        const int cg = mgrp * 8 + mt;
        float Acomb = 1.f, Bcomb = 0.f;
#pragma unroll
        for (int mf = 0; mf < 4; ++mf) {
            float As = 1.f, Bs = 0.f;
            uint4 ov;
#pragma unroll
            for (int j = 0; j < 4; ++j) {
                float kv = acck[mf][j] + bzv;
                float pv = accp[mf][j] + bhv;
                float av = 1.0f / (1.0f + __expf(kv));           // 1-z = sigmoid(-k)
                float zv = 1.0f - av;
                float gv = (pv >= 0.0f) ? (pv + 0.5f) : (1.0f / (1.0f + __expf(-pv)));
                float bvv = zv * gv;
                __half2 hp = __floats2half2_rn(av, bvv);
                ((unsigned*)&ov)[j] = *(unsigned*)&hp;
                Bs = fmaf(av, Bs, bvv);
                As *= av;
            }
            pkf[((size_t)cg * 32 + ns) * 4 * 64 + (size_t)mf * 64 + lane] = ov;
            // compose 4 lane-groups in time order (lg ascending)
            float Ag = 1.f, Bg = 0.f;
#pragma unroll
            for (int g = 0; g < 4; ++g) {
                float Ai = __shfl(As, lr + g * 16, 64);
                float Bi = __shfl(Bs, lr + g * 16, 64);
                Bg = fmaf(Ai, Bg, Bi);
                Ag *= Ai;
            }
            Bcomb = fmaf(Ag, Bcomb, Bg);
            Acomb *= Ag;
        }
        if (lg == 0)
            agg[(size_t)cg * 512 + h] = make_float2(Acomb, Bcomb);
    }
}

// Phase 2: sequential scan over chunk aggregates, emitting carry-in per chunk.
__global__ void scan_p2(const float* __restrict__ h0, const float2* __restrict__ agg,
                        float* __restrict__ carry) {
    int g = blockIdx.x * 256 + threadIdx.x;   // 0..2047
    int b = g >> 9, h = g & 511;
    float v = h0[b * 512 + h];
    float s = (v >= 0.f) ? (v + 0.5f) : (1.f / (1.f + __expf(-v)));   // g(h_0)
    for (int c = 0; c < NC; ++c) {
        size_t o = ((size_t)(b * NC + c)) * 512 + h;
        carry[o] = s;
        float2 ab = agg[o];
        s = fmaf(ab.x, s, ab.y);
    }
}

// Phase 3: replay recurrence within chunk from frag-ordered half2 (a,b), write h.
// Thread: lr=tid&15, nsl=(tid>>4)&3, w=tid>>6; handles h=(w*4+nsl)*16+lr and h+256.
__global__ void scan_p3(const float* __restrict__ carry, const uint4* __restrict__ pkf,
                        float* __restrict__ out) {
    int c = blockIdx.x, b = blockIdx.y;
    int tid = threadIdx.x;
    int lr = tid & 15, nsl = (tid >> 4) & 3, w = tid >> 6;
    int nsa = w * 4 + nsl, nsb = nsa + 16;
    int ha = nsa * 16 + lr, hb = ha + 256;
    int cg = b * NC + c;
    size_t co = (size_t)cg * 512;
    float s0 = carry[co + ha], s1 = carry[co + hb];
    size_t cb = (size_t)cg * 8192;            // uint4 units: 32 ns * 4 mf * 64 lanes
    size_t ob = (size_t)cg * 64 * 512;        // == (b*LL + c*64)*512
#pragma unroll
    for (int mf = 0; mf < 4; ++mf) {
#pragma unroll
        for (int lg = 0; lg < 4; ++lg) {
            uint4 fa = pkf[cb + ((size_t)nsa * 4 + mf) * 64 + lg * 16 + lr];
            uint4 fb = pkf[cb + ((size_t)nsb * 4 + mf) * 64 + lg * 16 + lr];
#pragma unroll
            for (int j = 0; j < 4; ++j) {
                int t = mf * 16 + lg * 4 + j;
                unsigned ua = ((unsigned*)&fa)[j];
                unsigned ub = ((unsigned*)&fb)[j];
                float2 ab0 = __half22float2(*(__half2*)&ua);
                float2 ab1 = __half22float2(*(__half2*)&ub);
                s0 = fmaf(ab0.x, s0, ab0.y);
                s1 = fmaf(ab1.x, s1, ab1.y);
                out[ob + (size_t)t * 512 + ha] = s0;
                out[ob + (size_t)t * 512 + hb] = s1;
            }
        }
    }
}

extern "C" void kernel_launch(void* const* d_in, const int* in_sizes, int n_in,
                              void* d_out, int out_size, void* d_ws, size_t ws_size,
                              hipStream_t stream) {
    const float* x  = (const float*)d_in[0];
    const float* h0 = (const float*)d_in[1];
    const float* Wz = (const float*)d_in[2];
    const float* bz = (const float*)d_in[3];
    const float* Wh = (const float*)d_in[4];
    const float* bh = (const float*)d_in[5];
    float* out = (float*)d_out;

    // workspace layout (~100 MB)
    unsigned short* xfb = (unsigned short*)d_ws;                 // 32 MB (frag-ordered x)
    unsigned short* wzf = xfb + (size_t)MM * 512;                // 0.5 MB
    unsigned short* whf = wzf + (size_t)512 * 512;               // 0.5 MB
    uint4* pkf   = (uint4*)(whf + (size_t)512 * 512);            // 64 MB
    float2* agg  = (float2*)((char*)pkf + (size_t)MM * 512 * 4); // 2 MB
    float* carry = (float*)(agg + (size_t)BB * NC * 512);        // 1 MB

    cvt_xfrag<<<8192, 256, 0, stream>>>(x, xfb);
    cvt_wfrag<<<256, 256, 0, stream>>>(Wz, Wh, wzf, whf);
    gemm_gate<<<512, 256, 0, stream>>>(xfb, wzf, whf, bz, bh, pkf, agg);
    scan_p2<<<8, 256, 0, stream>>>(h0, agg, carry);
    scan_p3<<<dim3(NC, BB), 256, 0, stream>>>(carry, pkf, out);
}

// Round 5
// 132.279 us; speedup vs baseline: 1.0949x; 1.0949x over previous
//
#include <hip/hip_runtime.h>
#include <hip/hip_bf16.h>
#include <hip/hip_fp16.h>

// minGRU parallel scan, B=4 L=8192 DX=512 DH=512.
// h_t = a_t h_{t-1} + b_t, a=sigmoid(-k), b=sigmoid(k)*g(p); linear-space chunked scan.
// R5: R4 barrier-free streaming GEMM + XCD-coherent block remap: the 8 blocks
// sharing an x m-slice all have bx ≡ mgrp (mod 8) -> same XCD L2 (one HBM fetch).

#define BB 4
#define LL 8192
#define MM (BB*LL)        // 32768 rows
#define NC 128            // chunks per batch
#define CHUNK 64          // L / NC

typedef __attribute__((ext_vector_type(8))) short bf16x8;
typedef __attribute__((ext_vector_type(4))) float f32x4;

__device__ inline unsigned f2bf(float f) {
    unsigned u = __float_as_uint(f);
    return ((u + 0x7FFFu + ((u >> 16) & 1u)) >> 16) & 0xFFFFu;
}

// x f32 [row][k] -> bf16 A-fragment order:
// frag f = rb*16 + kstep (rb = row/16, kstep = k/32), lane = lg*16 + (row&15),
// holds x[row][kstep*32 + lg*8 .. +8]. Stored at xf[f*512 + lane*8].
__global__ void cvt_xfrag(const float* __restrict__ in, unsigned short* __restrict__ out) {
    int t = blockIdx.x * 256 + threadIdx.x;     // 0 .. 2M-1
    int lane = t & 63, f = t >> 6;
    int kstep = f & 15, rb = f >> 4;
    int row = rb * 16 + (lane & 15);
    int k = kstep * 32 + (lane >> 4) * 8;
    const float* p = in + (size_t)row * 512 + k;
    float4 v0 = *(const float4*)p;
    float4 v1 = *(const float4*)(p + 4);
    uint4 o;
    o.x = f2bf(v0.x) | (f2bf(v0.y) << 16);
    o.y = f2bf(v0.z) | (f2bf(v0.w) << 16);
    o.z = f2bf(v1.x) | (f2bf(v1.y) << 16);
    o.w = f2bf(v1.z) | (f2bf(v1.w) << 16);
    *(uint4*)(out + (size_t)t * 8) = o;
}

// Pack both weights into MFMA B-fragment order (validated R3):
// frag u = (((ntile*8 + ks)*2 + kk)*8 + nf2)*64 + lane holds W[n][k..k+8],
// n = ntile*128 + nf2*16 + (lane&15), k = ks*64 + kk*32 + (lane>>4)*8.
__global__ void cvt_wfrag(const float* __restrict__ Wz, const float* __restrict__ Wh,
                          unsigned short* __restrict__ wzf, unsigned short* __restrict__ whf) {
    int t = blockIdx.x * 256 + threadIdx.x;    // 0..65535
    int wsel = t >> 15;
    int u = t & 32767;
    int lane = u & 63, lg = lane >> 4, lr = lane & 15;
    int nf2 = (u >> 6) & 7;
    int kk = (u >> 9) & 1;
    int ks = (u >> 10) & 7;
    int ntile = (u >> 13) & 3;
    int n = ntile * 128 + nf2 * 16 + lr;
    int k = ks * 64 + kk * 32 + lg * 8;
    const float* W = wsel ? Wh : Wz;
    unsigned short* o = wsel ? whf : wzf;
    const float* p = W + (size_t)n * 512 + k;
    float4 v0 = *(const float4*)p;
    float4 v1 = *(const float4*)(p + 4);
    uint4 ov;
    ov.x = f2bf(v0.x) | (f2bf(v0.y) << 16);
    ov.y = f2bf(v0.z) | (f2bf(v0.w) << 16);
    ov.z = f2bf(v1.x) | (f2bf(v1.y) << 16);
    ov.w = f2bf(v1.z) | (f2bf(v1.w) << 16);
    *(uint4*)(o + (size_t)u * 8) = ov;
}

// Barrier-free streaming GEMM + gate epilogue + fused chunk aggregates.
// Block = 4 waves; wave owns n-slice ns (16 cols), full K in registers.
// grid.x = 512: npart = bx>>6 (slow), mgrp = bx&63 (fast) -> the 8 blocks sharing
// x rows [mgrp*512, mgrp*512+512) are bx ≡ mgrp (mod 8): same XCD, one L2 copy.
__global__ __launch_bounds__(256, 2) void gemm_gate(
    const unsigned short* __restrict__ xf, const unsigned short* __restrict__ wzf,
    const unsigned short* __restrict__ whf,
    const float* __restrict__ bz, const float* __restrict__ bh,
    uint4* __restrict__ pkf, float2* __restrict__ agg)
{
    const int tid = threadIdx.x;
    const int wid = tid >> 6, lane = tid & 63;
    const int lr = lane & 15, lg = lane >> 4;
    const int npart = blockIdx.x >> 6;
    const int mgrp  = blockIdx.x & 63;
    const int ns = npart * 4 + wid;            // 0..31

    // Load both weight matrices' fragments for this n-slice, full K: 128 VGPRs.
    bf16x8 wz[16], wh[16];
#pragma unroll
    for (int kstep = 0; kstep < 16; ++kstep) {
        int ks = kstep >> 1, kk = kstep & 1;
        size_t fo = ((((size_t)(ns >> 3) * 8 + ks) * 2 + kk) * 8 + (ns & 7)) * 512 + lane * 8;
        wz[kstep] = *(const bf16x8*)(wzf + fo);
        wh[kstep] = *(const bf16x8*)(whf + fo);
    }
    const int h = ns * 16 + lr;
    const float bzv = bz[h], bhv = bh[h];

    for (int mt = 0; mt < 8; ++mt) {
        const int rb0 = mgrp * 32 + mt * 4;                 // row-block (16 rows each)
        const unsigned short* xb = xf + (size_t)rb0 * 16 * 512 + lane * 8;
        f32x4 acck[4] = {{0.f,0.f,0.f,0.f},{0.f,0.f,0.f,0.f},{0.f,0.f,0.f,0.f},{0.f,0.f,0.f,0.f}};
        f32x4 accp[4] = {{0.f,0.f,0.f,0.f},{0.f,0.f,0.f,0.f},{0.f,0.f,0.f,0.f},{0.f,0.f,0.f,0.f}};
        bf16x8 af[4][4];                                    // [pipeline slot][mf], all-static idx
#pragma unroll
        for (int d = 0; d < 4; ++d)
#pragma unroll
            for (int mf = 0; mf < 4; ++mf)
                af[d][mf] = *(const bf16x8*)(xb + ((size_t)mf * 16 + d) * 512);
#pragma unroll
        for (int kstep = 0; kstep < 16; ++kstep) {
            const int s = kstep & 3;
#pragma unroll
            for (int mf = 0; mf < 4; ++mf) {
                acck[mf] = __builtin_amdgcn_mfma_f32_16x16x32_bf16(af[s][mf], wz[kstep], acck[mf], 0, 0, 0);
                accp[mf] = __builtin_amdgcn_mfma_f32_16x16x32_bf16(af[s][mf], wh[kstep], accp[mf], 0, 0, 0);
            }
            if (kstep < 12) {
#pragma unroll
                for (int mf = 0; mf < 4; ++mf)
                    af[s][mf] = *(const bf16x8*)(xb + ((size_t)mf * 16 + kstep + 4) * 512);
            }
        }

        // Epilogue. C/D layout: col=lane&15 (=h-lr), row=(lane>>4)*4+j [m89-verified].
        // This m-tile is exactly chunk cg = mgrp*8 + mt (= b*128 + c).
        const int cg = mgrp * 8 + mt;
        float Acomb = 1.f, Bcomb = 0.f;
#pragma unroll
        for (int mf = 0; mf < 4; ++mf) {
            float As = 1.f, Bs = 0.f;
            uint4 ov;
#pragma unroll
            for (int j = 0; j < 4; ++j) {
                float kv = acck[mf][j] + bzv;
                float pv = accp[mf][j] + bhv;
                float av = 1.0f / (1.0f + __expf(kv));           // 1-z = sigmoid(-k)
                float zv = 1.0f - av;
                float gv = (pv >= 0.0f) ? (pv + 0.5f) : (1.0f / (1.0f + __expf(-pv)));
                float bvv = zv * gv;
                __half2 hp = __floats2half2_rn(av, bvv);
                ((unsigned*)&ov)[j] = *(unsigned*)&hp;
                Bs = fmaf(av, Bs, bvv);
                As *= av;
            }
            pkf[((size_t)cg * 32 + ns) * 4 * 64 + (size_t)mf * 64 + lane] = ov;
            // compose 4 lane-groups in time order (lg ascending)
            float Ag = 1.f, Bg = 0.f;
#pragma unroll
            for (int g = 0; g < 4; ++g) {
                float Ai = __shfl(As, lr + g * 16, 64);
                float Bi = __shfl(Bs, lr + g * 16, 64);
                Bg = fmaf(Ai, Bg, Bi);
                Ag *= Ai;
            }
            Bcomb = fmaf(Ag, Bcomb, Bg);
            Acomb *= Ag;
        }
        if (lg == 0)
            agg[(size_t)cg * 512 + h] = make_float2(Acomb, Bcomb);
    }
}

// Phase 2: sequential scan over chunk aggregates, emitting carry-in per chunk.
__global__ void scan_p2(const float* __restrict__ h0, const float2* __restrict__ agg,
                        float* __restrict__ carry) {
    int g = blockIdx.x * 256 + threadIdx.x;   // 0..2047
    int b = g >> 9, h = g & 511;
    float v = h0[b * 512 + h];
    float s = (v >= 0.f) ? (v + 0.5f) : (1.f / (1.f + __expf(-v)));   // g(h_0)
    for (int c = 0; c < NC; ++c) {
        size_t o = ((size_t)(b * NC + c)) * 512 + h;
        carry[o] = s;
        float2 ab = agg[o];
        s = fmaf(ab.x, s, ab.y);
    }
}

// Phase 3: replay recurrence within chunk from frag-ordered half2 (a,b), write h.
// Thread: lr=tid&15, nsl=(tid>>4)&3, w=tid>>6; handles h=(w*4+nsl)*16+lr and h+256.
__global__ void scan_p3(const float* __restrict__ carry, const uint4* __restrict__ pkf,
                        float* __restrict__ out) {
    int c = blockIdx.x, b = blockIdx.y;
    int tid = threadIdx.x;
    int lr = tid & 15, nsl = (tid >> 4) & 3, w = tid >> 6;
    int nsa = w * 4 + nsl, nsb = nsa + 16;
    int ha = nsa * 16 + lr, hb = ha + 256;
    int cg = b * NC + c;
    size_t co = (size_t)cg * 512;
    float s0 = carry[co + ha], s1 = carry[co + hb];
    size_t cb = (size_t)cg * 8192;            // uint4 units: 32 ns * 4 mf * 64 lanes
    size_t ob = (size_t)cg * 64 * 512;        // == (b*LL + c*64)*512
#pragma unroll
    for (int mf = 0; mf < 4; ++mf) {
#pragma unroll
        for (int lg = 0; lg < 4; ++lg) {
            uint4 fa = pkf[cb + ((size_t)nsa * 4 + mf) * 64 + lg * 16 + lr];
            uint4 fb = pkf[cb + ((size_t)nsb * 4 + mf) * 64 + lg * 16 + lr];
#pragma unroll
            for (int j = 0; j < 4; ++j) {
                int t = mf * 16 + lg * 4 + j;
                unsigned ua = ((unsigned*)&fa)[j];
                unsigned ub = ((unsigned*)&fb)[j];
                float2 ab0 = __half22float2(*(__half2*)&ua);
                float2 ab1 = __half22float2(*(__half2*)&ub);
                s0 = fmaf(ab0.x, s0, ab0.y);
                s1 = fmaf(ab1.x, s1, ab1.y);
                out[ob + (size_t)t * 512 + ha] = s0;
                out[ob + (size_t)t * 512 + hb] = s1;
            }
        }
    }
}

extern "C" void kernel_launch(void* const* d_in, const int* in_sizes, int n_in,
                              void* d_out, int out_size, void* d_ws, size_t ws_size,
                              hipStream_t stream) {
    const float* x  = (const float*)d_in[0];
    const float* h0 = (const float*)d_in[1];
    const float* Wz = (const float*)d_in[2];
    const float* bz = (const float*)d_in[3];
    const float* Wh = (const float*)d_in[4];
    const float* bh = (const float*)d_in[5];
    float* out = (float*)d_out;

    // workspace layout (~100 MB)
    unsigned short* xfb = (unsigned short*)d_ws;                 // 32 MB (frag-ordered x)
    unsigned short* wzf = xfb + (size_t)MM * 512;                // 0.5 MB
    unsigned short* whf = wzf + (size_t)512 * 512;               // 0.5 MB
    uint4* pkf   = (uint4*)(whf + (size_t)512 * 512);            // 64 MB
    float2* agg  = (float2*)((char*)pkf + (size_t)MM * 512 * 4); // 2 MB
    float* carry = (float*)(agg + (size_t)BB * NC * 512);        // 1 MB

    cvt_xfrag<<<8192, 256, 0, stream>>>(x, xfb);
    cvt_wfrag<<<256, 256, 0, stream>>>(Wz, Wh, wzf, whf);
    gemm_gate<<<512, 256, 0, stream>>>(xfb, wzf, whf, bz, bh, pkf, agg);
    scan_p2<<<8, 256, 0, stream>>>(h0, agg, carry);
    scan_p3<<<dim3(NC, BB), 256, 0, stream>>>(carry, pkf, out);
}

// Round 6
// 105.204 us; speedup vs baseline: 1.3767x; 1.2574x over previous
//
#include <hip/hip_runtime.h>
#include <hip/hip_bf16.h>
#include <hip/hip_fp16.h>

// minGRU parallel scan, B=4 L=8192 DX=512 DH=512.
// h_t = a_t h_{t-1} + b_t, a=sigmoid(-k), b=sigmoid(k)*g(p); linear-space chunked scan.
// R6: 8-wave block, weights-in-VGPR (full K, 128 regs/wave), x staged through
// double-buffered LDS via global_load_lds (XOR-swizzled global layout) so the
// 8 waves share one L2 read instead of 8. Grid 256 = 4 nparts x 64 mgrps,
// XCD-coherent (sharers of an mgrp differ by 64 in bx -> same XCD L2).

#define BB 4
#define LL 8192
#define MM (BB*LL)        // 32768 rows
#define NC 128            // chunks per batch
#define CHUNK 64          // L / NC

typedef __attribute__((ext_vector_type(8))) short bf16x8;
typedef __attribute__((ext_vector_type(4))) float f32x4;

__device__ inline unsigned f2bf(float f) {
    unsigned u = __float_as_uint(f);
    return ((u + 0x7FFFu + ((u >> 16) & 1u)) >> 16) & 0xFFFFu;
}

// f32 -> bf16, XOR chunk-swizzle baked into the GLOBAL layout (validated R2):
// 8-elem unit (seg*8+sub) of row l stored at unit seg*8 + (sub^(l&7)).
// A linear global_load_lds copy then lands pre-swizzled in LDS.
__global__ void cvt_swz(const float* __restrict__ in, unsigned short* __restrict__ out, int rows) {
    int t = blockIdx.x * 256 + threadIdx.x;
    if (t >= rows * 64) return;
    int l = t >> 6, c = t & 63;
    int seg = c >> 3, sub = c & 7;
    int q = sub ^ (l & 7);
    const float* p = in + (size_t)l * 512 + c * 8;
    float4 v0 = *(const float4*)p;
    float4 v1 = *(const float4*)(p + 4);
    uint4 o;
    o.x = f2bf(v0.x) | (f2bf(v0.y) << 16);
    o.y = f2bf(v0.z) | (f2bf(v0.w) << 16);
    o.z = f2bf(v1.x) | (f2bf(v1.y) << 16);
    o.w = f2bf(v1.z) | (f2bf(v1.w) << 16);
    *(uint4*)(out + (size_t)l * 512 + seg * 64 + q * 8) = o;
}

// Pack both weights into MFMA B-fragment order (validated R3):
// frag u = (((ntile*8 + ks)*2 + kk)*8 + nf2)*64 + lane holds W[n][k..k+8],
// n = ntile*128 + nf2*16 + (lane&15), k = ks*64 + kk*32 + (lane>>4)*8.
__global__ void cvt_wfrag(const float* __restrict__ Wz, const float* __restrict__ Wh,
                          unsigned short* __restrict__ wzf, unsigned short* __restrict__ whf) {
    int t = blockIdx.x * 256 + threadIdx.x;    // 0..65535
    int wsel = t >> 15;
    int u = t & 32767;
    int lane = u & 63, lg = lane >> 4, lr = lane & 15;
    int nf2 = (u >> 6) & 7;
    int kk = (u >> 9) & 1;
    int ks = (u >> 10) & 7;
    int ntile = (u >> 13) & 3;
    int n = ntile * 128 + nf2 * 16 + lr;
    int k = ks * 64 + kk * 32 + lg * 8;
    const float* W = wsel ? Wh : Wz;
    unsigned short* o = wsel ? whf : wzf;
    const float* p = W + (size_t)n * 512 + k;
    float4 v0 = *(const float4*)p;
    float4 v1 = *(const float4*)(p + 4);
    uint4 ov;
    ov.x = f2bf(v0.x) | (f2bf(v0.y) << 16);
    ov.y = f2bf(v0.z) | (f2bf(v0.w) << 16);
    ov.z = f2bf(v1.x) | (f2bf(v1.y) << 16);
    ov.w = f2bf(v1.z) | (f2bf(v1.w) << 16);
    *(uint4*)(o + (size_t)u * 8) = ov;
}

#define GLDS(g, l) __builtin_amdgcn_global_load_lds( \
    (const __attribute__((address_space(1))) unsigned int*)(g), \
    (__attribute__((address_space(3))) unsigned int*)(l), 16, 0, 0)

// 8 waves x 16 n-cols = 128 cols/block; m-group = 512 rows = 8 mt-tiles of 64.
// grid 256: npart = bx>>6 (0..3), mgrp = bx&63. Weights full-K in 128 VGPR/wave.
// x: 64KB mt-tile double-buffered in LDS (128 KB), staged with global_load_lds.
__global__ __launch_bounds__(512, 2) void gemm_gate(
    const unsigned short* __restrict__ xs, const unsigned short* __restrict__ wzf,
    const unsigned short* __restrict__ whf,
    const float* __restrict__ bz, const float* __restrict__ bh,
    uint4* __restrict__ pkf, float2* __restrict__ agg)
{
    extern __shared__ char smem[];             // 2 x 65536 B
    const int tid = threadIdx.x;
    const int wid = tid >> 6, lane = tid & 63;
    const int lr = lane & 15, lg = lane >> 4;
    const int npart = blockIdx.x >> 6;
    const int mgrp  = blockIdx.x & 63;
    const int ns = npart * 8 + wid;            // n-slice 0..31 (16 cols each)

    // Weights for this n-slice, full K, both matrices: 128 VGPRs.
    bf16x8 wz[16], wh[16];
#pragma unroll
    for (int kstep = 0; kstep < 16; ++kstep) {
        int ks = kstep >> 1, kk = kstep & 1;
        size_t fo = ((((size_t)(ns >> 3) * 8 + ks) * 2 + kk) * 8 + (ns & 7)) * 512 + lane * 8;
        wz[kstep] = *(const bf16x8*)(wzf + fo);
        wh[kstep] = *(const bf16x8*)(whf + fo);
    }
    const int h = ns * 16 + lr;
    const float bzv = bz[h], bhv = bh[h];
    const char* xbase = (const char*)xs + (size_t)mgrp * 512 * 1024;

#define STAGE(buf, mt) do { \
    _Pragma("unroll") \
    for (int p = 0; p < 8; ++p) { \
        int o = (p * 512 + tid) * 16; \
        GLDS(xbase + (size_t)(mt) * 65536 + o, smem + (buf) * 65536 + o); \
    } } while (0)

    STAGE(0, 0);
    __syncthreads();

    for (int mt = 0; mt < 8; ++mt) {
        const int cur = mt & 1;
        if (mt < 7) STAGE(cur ^ 1, mt + 1);    // issue early; drained by end barrier

        f32x4 acck[4] = {{0.f,0.f,0.f,0.f},{0.f,0.f,0.f,0.f},{0.f,0.f,0.f,0.f},{0.f,0.f,0.f,0.f}};
        f32x4 accp[4] = {{0.f,0.f,0.f,0.f},{0.f,0.f,0.f,0.f},{0.f,0.f,0.f,0.f},{0.f,0.f,0.f,0.f}};
        const char* lb = smem + cur * 65536;   // [64 rows][1024 B], data pre-swizzled

        // A-frag read: row r=mf*16+lr, unit q=(kstep*4+lg)^(lr&7): 2-way banks (free).
        bf16x8 af[2][4];
#pragma unroll
        for (int mf = 0; mf < 4; ++mf)
            af[0][mf] = *(const bf16x8*)(lb + (mf * 16 + lr) * 1024 + ((0 * 4 + lg) ^ (lr & 7)) * 16);
#pragma unroll
        for (int kstep = 0; kstep < 16; ++kstep) {
            const int sl = kstep & 1;
            if (kstep < 15) {
#pragma unroll
                for (int mf = 0; mf < 4; ++mf)
                    af[sl ^ 1][mf] = *(const bf16x8*)(lb + (mf * 16 + lr) * 1024
                                        + (((kstep + 1) * 4 + lg) ^ (lr & 7)) * 16);
            }
#pragma unroll
            for (int mf = 0; mf < 4; ++mf) {
                acck[mf] = __builtin_amdgcn_mfma_f32_16x16x32_bf16(af[sl][mf], wz[kstep], acck[mf], 0, 0, 0);
                accp[mf] = __builtin_amdgcn_mfma_f32_16x16x32_bf16(af[sl][mf], wh[kstep], accp[mf], 0, 0, 0);
            }
        }

        // Epilogue (no LDS): C/D layout col=lane&15, row=(lane>>4)*4+j [m89-verified].
        // This mt-tile is exactly chunk cg = mgrp*8 + mt.
        const int cg = mgrp * 8 + mt;
        float Acomb = 1.f, Bcomb = 0.f;
#pragma unroll
        for (int mf = 0; mf < 4; ++mf) {
            float As = 1.f, Bs = 0.f;
            uint4 ov;
#pragma unroll
            for (int j = 0; j < 4; ++j) {
                float kv = acck[mf][j] + bzv;
                float pv = accp[mf][j] + bhv;
                float av = 1.0f / (1.0f + __expf(kv));           // 1-z = sigmoid(-k)
                float zv = 1.0f - av;
                float gv = (pv >= 0.0f) ? (pv + 0.5f) : (1.0f / (1.0f + __expf(-pv)));
                float bvv = zv * gv;
                __half2 hp = __floats2half2_rn(av, bvv);
                ((unsigned*)&ov)[j] = *(unsigned*)&hp;
                Bs = fmaf(av, Bs, bvv);
                As *= av;
            }
            pkf[((size_t)cg * 32 + ns) * 4 * 64 + (size_t)mf * 64 + lane] = ov;
            // compose 4 lane-groups in time order (lg ascending)
            float Ag = 1.f, Bg = 0.f;
#pragma unroll
            for (int g = 0; g < 4; ++g) {
                float Ai = __shfl(As, lr + g * 16, 64);
                float Bi = __shfl(Bs, lr + g * 16, 64);
                Bg = fmaf(Ai, Bg, Bi);
                Ag *= Ai;
            }
            Bcomb = fmaf(Ag, Bcomb, Bg);
            Acomb *= Ag;
        }
        if (lg == 0)
            agg[(size_t)cg * 512 + h] = make_float2(Acomb, Bcomb);

        __syncthreads();   // next buffer staged; all reads of cur done
    }
}

// Phase 2: sequential scan over chunk aggregates, emitting carry-in per chunk.
__global__ void scan_p2(const float* __restrict__ h0, const float2* __restrict__ agg,
                        float* __restrict__ carry) {
    int g = blockIdx.x * 256 + threadIdx.x;   // 0..2047
    int b = g >> 9, h = g & 511;
    float v = h0[b * 512 + h];
    float s = (v >= 0.f) ? (v + 0.5f) : (1.f / (1.f + __expf(-v)));   // g(h_0)
    for (int c = 0; c < NC; ++c) {
        size_t o = ((size_t)(b * NC + c)) * 512 + h;
        carry[o] = s;
        float2 ab = agg[o];
        s = fmaf(ab.x, s, ab.y);
    }
}

// Phase 3: replay recurrence within chunk from frag-ordered half2 (a,b), write h.
// Thread: lr=tid&15, nsl=(tid>>4)&3, w=tid>>6; handles h=(w*4+nsl)*16+lr and h+256.
__global__ void scan_p3(const float* __restrict__ carry, const uint4* __restrict__ pkf,
                        float* __restrict__ out) {
    int c = blockIdx.x, b = blockIdx.y;
    int tid = threadIdx.x;
    int lr = tid & 15, nsl = (tid >> 4) & 3, w = tid >> 6;
    int nsa = w * 4 + nsl, nsb = nsa + 16;
    int ha = nsa * 16 + lr, hb = ha + 256;
    int cg = b * NC + c;
    size_t co = (size_t)cg * 512;
    float s0 = carry[co + ha], s1 = carry[co + hb];
    size_t cb = (size_t)cg * 8192;            // uint4 units: 32 ns * 4 mf * 64 lanes
    size_t ob = (size_t)cg * 64 * 512;        // == (b*LL + c*64)*512
#pragma unroll
    for (int mf = 0; mf < 4; ++mf) {
#pragma unroll
        for (int lg = 0; lg < 4; ++lg) {
            uint4 fa = pkf[cb + ((size_t)nsa * 4 + mf) * 64 + lg * 16 + lr];
            uint4 fb = pkf[cb + ((size_t)nsb * 4 + mf) * 64 + lg * 16 + lr];
#pragma unroll
            for (int j = 0; j < 4; ++j) {
                int t = mf * 16 + lg * 4 + j;
                unsigned ua = ((unsigned*)&fa)[j];
                unsigned ub = ((unsigned*)&fb)[j];
                float2 ab0 = __half22float2(*(__half2*)&ua);
                float2 ab1 = __half22float2(*(__half2*)&ub);
                s0 = fmaf(ab0.x, s0, ab0.y);
                s1 = fmaf(ab1.x, s1, ab1.y);
                out[ob + (size_t)t * 512 + ha] = s0;
                out[ob + (size_t)t * 512 + hb] = s1;
            }
        }
    }
}

extern "C" void kernel_launch(void* const* d_in, const int* in_sizes, int n_in,
                              void* d_out, int out_size, void* d_ws, size_t ws_size,
                              hipStream_t stream) {
    const float* x  = (const float*)d_in[0];
    const float* h0 = (const float*)d_in[1];
    const float* Wz = (const float*)d_in[2];
    const float* bz = (const float*)d_in[3];
    const float* Wh = (const float*)d_in[4];
    const float* bh = (const float*)d_in[5];
    float* out = (float*)d_out;

    // workspace layout (~100 MB)
    unsigned short* xs  = (unsigned short*)d_ws;                 // 32 MB (row-major swizzled)
    unsigned short* wzf = xs + (size_t)MM * 512;                 // 0.5 MB
    unsigned short* whf = wzf + (size_t)512 * 512;               // 0.5 MB
    uint4* pkf   = (uint4*)(whf + (size_t)512 * 512);            // 64 MB
    float2* agg  = (float2*)((char*)pkf + (size_t)MM * 512 * 4); // 2 MB
    float* carry = (float*)(agg + (size_t)BB * NC * 512);        // 1 MB

    cvt_swz<<<8192, 256, 0, stream>>>(x, xs, MM);
    cvt_wfrag<<<256, 256, 0, stream>>>(Wz, Wh, wzf, whf);
    gemm_gate<<<256, 512, 131072, stream>>>(xs, wzf, whf, bz, bh, pkf, agg);
    scan_p2<<<8, 256, 0, stream>>>(h0, agg, carry);
    scan_p3<<<dim3(NC, BB), 256, 0, stream>>>(carry, pkf, out);
}